// Round 15
// baseline (200.582 us; speedup 1.0000x reference)
//
#include <hip/hip_runtime.h>

#define NN 2000
#define TT 12

// workspace layout (in floats)
#define XOFF    0          // x buffer f16: (B,N,T,C) f16 = 6,144,000 floats
#define SKOFF   6144000    // skip: (B,N,C) f32
#define CHOFF   7168000    // ch: N*4
#define CMOFF   7176000    // char_m: N*4
#define STOFF   7184000    // stats: 96
#define PKWOFF  7184100    // packed conv+gate rank weights f32 [layer][o][u][c]: 13824*8
#define PKBOFF  7294692    // packed conv+gate rank biases f32 [layer][o][u][c]: 13824*2
#define PKROFF  7322340    // packed residual rank weights f32: 3072*8

typedef __fp16 f16x8 __attribute__((ext_vector_type(8)));
typedef __fp16 h2    __attribute__((ext_vector_type(2)));
typedef float  f32x4 __attribute__((ext_vector_type(4)));

union U32H2 { unsigned int u; __fp16 h[2]; h2 v; };
__device__ __forceinline__ unsigned int pkh(float a, float b){
  U32H2 x; x.h[0] = (__fp16)a; x.h[1] = (__fp16)b; return x.u;
}
__device__ __forceinline__ h2 u2h(unsigned int u){ U32H2 x; x.u = u; return x.v; }
__device__ __forceinline__ unsigned int h2u(h2 v){ U32H2 x; x.v = v; return x.u; }
__device__ __forceinline__ float fsig(float x){ return 1.0f/(1.0f + __expf(-x)); }
__device__ __forceinline__ float ftanh(float x){ return 1.0f - 2.0f/(1.0f + __expf(2.0f*x)); }

__global__ void k_init(float* stats){
  int t = threadIdx.x;
  if (t < 96) stats[t] = 0.0f;
}

// fused: weight packing (cols < 13824) + month-characteristic mean (idx < 8000)
__global__ __launch_bounds__(256) void k_prep(
    const float* __restrict__ Wcw, const float* __restrict__ bcw,
    const float* __restrict__ Wgw, const float* __restrict__ bgw,
    const float* __restrict__ Wrw, const float* __restrict__ brw,
    const float* __restrict__ input, const float* __restrict__ charac,
    float* __restrict__ PKW, float* __restrict__ PKB, float* __restrict__ PKR,
    float* __restrict__ cm)
{
  int col = blockIdx.x*256 + threadIdx.x;
  if (col < 13824){
    int layer = col / 4608;
    int i     = col - layer*4608;
    int o     = i / 576;
    int rem   = i - o*576;
    int c     = rem / 18;
    int u     = rem - c*18;
    size_t j  = (size_t)layer*4608 + o*576 + u*32 + c;
    float4 a = make_float4(Wcw[col], Wcw[13824+col], Wcw[27648+col], Wcw[41472+col]);
    float4 b = make_float4(Wgw[col], Wgw[13824+col], Wgw[27648+col], Wgw[41472+col]);
    *reinterpret_cast<float4*>(PKW + j*8)     = a;
    *reinterpret_cast<float4*>(PKW + j*8 + 4) = b;
    *reinterpret_cast<float2*>(PKB + j*2) = make_float2(bcw[col], bgw[col]);
  }
  if (col < 3072){
    float4 r = make_float4(Wrw[col], Wrw[3072+col], Wrw[6144+col], Wrw[9216+col]);
    *reinterpret_cast<float4*>(PKR + (size_t)col*8) = r;
    PKR[(size_t)col*8 + 4] = brw[col];
  }
  if (col < NN*4){
    int n = col >> 2, r = col & 3;
    int mv = (int)input[TT];
    int m = ((mv % 12) + 12) % 12;
    int m0 = (m + 11) % 12, m2 = (m + 1) % 12;
    const float* base = charac + n*48;
    cm[col] = (base[m0*4+r] + base[m*4+r] + base[m2*4+r]) * (1.0f/3.0f);
  }
}

__global__ __launch_bounds__(256) void k_ch(const float* __restrict__ adj,
                                            const float* __restrict__ cm,
                                            float* __restrict__ ch)
{
  __shared__ float red[256][4];
  int n = blockIdx.x, t = threadIdx.x;
  float s0=0.f, s1=0.f, s2=0.f, s3=0.f;
  const float* arow = adj + (size_t)n*NN;
  for (int c = t; c < NN; c += 256){
    float a = arow[c];
    float4 v = *reinterpret_cast<const float4*>(cm + c*4);
    s0 = fmaf(a, v.x, s0); s1 = fmaf(a, v.y, s1);
    s2 = fmaf(a, v.z, s2); s3 = fmaf(a, v.w, s3);
  }
  red[t][0]=s0; red[t][1]=s1; red[t][2]=s2; red[t][3]=s3;
  __syncthreads();
  for (int off = 128; off > 0; off >>= 1){
    if (t < off){
      red[t][0]+=red[t+off][0]; red[t][1]+=red[t+off][1];
      red[t][2]+=red[t+off][2]; red[t][3]+=red[t+off][3];
    }
    __syncthreads();
  }
  if (t < 4) ch[n*4+t] = red[0][t];
}

// ---------------------------------------------------------------------------
// k_layer: R14 structure; stats via per-block atomicAdd (no k_stats kernel).
// ---------------------------------------------------------------------------
__global__ __launch_bounds__(256,3) void k_layer(
    int layer,
    __fp16* __restrict__ xbuf, float* __restrict__ skipbuf,
    const float* __restrict__ ch, float* __restrict__ stats,
    const float* __restrict__ input,
    const float* __restrict__ PKW, const float* __restrict__ PKB,
    const float* __restrict__ PKR,
    const float* __restrict__ Wcb, const float* __restrict__ bcb,
    const float* __restrict__ Wgb, const float* __restrict__ bgb,
    const float* __restrict__ Wrb, const float* __restrict__ brb,
    const float* __restrict__ start_w, const float* __restrict__ start_b,
    const float* __restrict__ sk0w, const float* __restrict__ sk0b,
    const float* __restrict__ skw_all, const float* __restrict__ skb_all,
    const float* __restrict__ lnw_all, const float* __restrict__ lnb_all)
{
  __shared__ __fp16 AhG[10752];      // A tiles, later gh overlay
  __shared__ __fp16 xh[7680];        // [t][b][c] stride 40
  __shared__ __fp16 rwh[1280];
  __shared__ float skred[1024];
  __shared__ float wred[128];
  __shared__ float ubuf[1280];
  __shared__ float skwv[384];
  __shared__ float skbv[32], fbias[32], gbias[32], rbv[32];
  __shared__ float muv[16], rsv[16];

  const int tid = threadIdx.x;
  const int n = blockIdx.x;

  float* swv  = ubuf;        // 64   (layer 0)
  float* sbv  = ubuf + 64;   // 32
  float* s0wv = ubuf + 96;   // 768
  float* s0bv = ubuf + 864;  // 32
  float* xin  = ubuf + 896;  // 384 = 16 b x 24
  __fp16* lnh = reinterpret_cast<__fp16*>(ubuf);  // layer>0: [0:384) lnw [t][c], [384:768) lnb

  const float c0v = ch[n*4+0], c1v = ch[n*4+1], c2v = ch[n*4+2], c3v = ch[n*4+3];

  // ---- phase 0 constants ----
  for (int i = tid; i < 32; i += 256) skbv[i] = skb_all[layer*32+i];
  for (int i = tid; i < 384; i += 256) skwv[i] = skw_all[layer*384+i];
  if (layer == 0){
    for (int i = tid; i < 64; i += 256) swv[i] = start_w[i];
    for (int i = tid; i < 32; i += 256){ sbv[i] = start_b[i]; s0bv[i] = sk0b[i]; }
    for (int i = tid; i < 768; i += 256) s0wv[i] = sk0w[i];
    for (int i = tid; i < 384; i += 256){
      int bb = i/24, r = i%24, d = r/12, t = r%12;
      xin[i] = input[(((size_t)bb*2 + d)*NN + n)*13 + t];
    }
  } else {
    for (int i = tid; i < 384; i += 256){
      int c = i/12, t = i%12;
      size_t o = (((size_t)(layer-1)*32 + c)*NN + n)*12 + t;
      lnh[t*32+c]       = (__fp16)lnw_all[o];
      lnh[384 + t*32+c] = (__fp16)lnb_all[o];
    }
    if (tid < 16){
      float S1 = stats[(layer-1)*32 + tid];
      float S2 = stats[(layer-1)*32 + 16 + tid];
      const float M = 768000.0f;
      float mu = S1 / M;
      muv[tid] = mu;
      rsv[tid] = rsqrtf(S2/M - mu*mu + 1e-5f);
    }
  }

  // ---- phase 1: weight gen, o = tid>>5 constant, u compile-time unrolled ----
  {
    const int cc = tid & 31;
    const int o  = tid >> 5;
    const int o104 = o*104, o232 = o*232;
    const float* pw  = PKW + (size_t)layer*4608*8 + ((size_t)o*576 + cc)*8;
    const float* pbp = PKB + (size_t)layer*4608*2 + ((size_t)o*576 + cc)*2;
#pragma unroll
    for (int u = 0; u < 18; ++u){
      const int s    = (u >= 2) + (u >= 5) + (u >= 11);
      const int lo   = (s == 0) ? 0 : ((s == 1) ? 2 : ((s == 2) ? 5 : 11));
      const int jj   = u - lo;
      const int strd = (s >= 2) ? 232 : 104;
      const int base = ((s >= 2) ? 3328 : 0) + ((s & 1) << 3)*strd + jj*32;
      const int ooff = (s >= 2) ? o232 : o104;
      float4 pwf = *reinterpret_cast<const float4*>(pw + (size_t)u*256);
      float4 pwg = *reinterpret_cast<const float4*>(pw + (size_t)u*256 + 4);
      float2 pb  = *reinterpret_cast<const float2*>(pbp + (size_t)u*64);
      float wf = fmaf(c0v, pwf.x, fmaf(c1v, pwf.y,
                 fmaf(c2v, pwf.z, fmaf(c3v, pwf.w, pb.x))));
      float wg = fmaf(c0v, pwg.x, fmaf(c1v, pwg.y,
                 fmaf(c2v, pwg.z, fmaf(c3v, pwg.w, pb.y))));
      AhG[base + ooff + cc]             = (__fp16)wf;
      AhG[base + ooff + cc + 16*strd]   = (__fp16)wg;
    }
  }
  // zero padding slots (s=0 jj=2; s=2 jj=6)
  for (int i = tid; i < 1024; i += 256){
    int grp = i >> 8, rem = i & 255, r = rem >> 5, c = rem & 31;
    int base = (grp < 2) ? 0 : 3328;
    int strd = (grp < 2) ? 104 : 232;
    int off  = (grp < 2) ? 64 : 192;
    int gofs = (grp & 1) ? 16*strd : 0;
    AhG[base + gofs + r*strd + off + c] = (__fp16)0.f;
  }
  for (int i = tid; i < 1024; i += 256){
    int col = layer*1024 + i;
    float4 pr = *reinterpret_cast<const float4*>(PKR + (size_t)col*8);
    float rb = PKR[(size_t)col*8 + 4];
    float v = fmaf(c0v, pr.x, fmaf(c1v, pr.y,
              fmaf(c2v, pr.z, fmaf(c3v, pr.w, rb))));
    rwh[(i>>5)*40 + (i&31)] = (__fp16)v;
  }
  if (tid < 96){
    int which = tid >> 5, oc = tid & 31;
    if (which < 2){
      int s = oc >> 3;
      int v = ((n&3)<<3) + (oc&7);             // bias reshuffle: column
      int col = layer*32 + v;
      float cb0 = ch[(s*500 + (n>>2))*4 + 0];
      float cb1 = ch[(s*500 + (n>>2))*4 + 1];
      float cb2 = ch[(s*500 + (n>>2))*4 + 2];
      float cb3 = ch[(s*500 + (n>>2))*4 + 3];
      const float* Wb = which ? Wgb : Wcb;
      const float* bb = which ? bgb : bcb;
      float out = fmaf(cb0, Wb[col], fmaf(cb1, Wb[96+col],
                  fmaf(cb2, Wb[192+col], fmaf(cb3, Wb[288+col], bb[col]))));
      if (which) gbias[oc] = out; else fbias[oc] = out;
    } else {
      int colr = layer*32 + oc;
      rbv[oc] = fmaf(c0v, Wrb[colr], fmaf(c1v, Wrb[96+colr],
                fmaf(c2v, Wrb[192+colr], fmaf(c3v, Wrb[288+colr], brb[colr]))));
    }
  }
  __syncthreads();

  // ---- staging: xh[t][b][c] f16 (layer>0 path fully packed f16) ----
  if (tid < 192){
    int b = tid & 15, t = tid >> 4;
    unsigned int pk[16];
    if (layer == 0){
      float xa = xin[b*24 + t], xb2 = xin[b*24 + 12 + t];
      float xv[32];
#pragma unroll
      for (int c = 0; c < 32; ++c)
        xv[c] = fmaf(swv[c*2], xa, fmaf(swv[c*2+1], xb2, sbv[c]));
#pragma unroll
      for (int j = 0; j < 16; ++j) pk[j] = pkh(xv[2*j], xv[2*j+1]);
    } else {
      const uint4* src = reinterpret_cast<const uint4*>(
          xbuf + (((size_t)b*NN + n)*12 + t)*32);
      uint4 u0 = src[0], u1 = src[1], u2 = src[2], u3 = src[3];
      unsigned int uu[16] = {u0.x,u0.y,u0.z,u0.w, u1.x,u1.y,u1.z,u1.w,
                             u2.x,u2.y,u2.z,u2.w, u3.x,u3.y,u3.z,u3.w};
      __fp16 muh = (__fp16)muv[b], rsh = (__fp16)rsv[b];
      h2 mu2; mu2.x = muh; mu2.y = muh;
      h2 rs2; rs2.x = rsh; rs2.y = rsh;
      const h2* lnw2 = reinterpret_cast<const h2*>(lnh + t*32);
      const h2* lnb2 = reinterpret_cast<const h2*>(lnh + 384 + t*32);
#pragma unroll
      for (int j = 0; j < 16; ++j){
        h2 v = u2h(uu[j]);
        h2 r = (v - mu2) * rs2;
        h2 x2 = r * lnw2[j] + lnb2[j];
        pk[j] = h2u(x2);
      }
    }
    uint4* dst = reinterpret_cast<uint4*>(&xh[(t*16 + b)*40]);
    dst[0] = make_uint4(pk[0], pk[1], pk[2], pk[3]);
    dst[1] = make_uint4(pk[4], pk[5], pk[6], pk[7]);
    dst[2] = make_uint4(pk[8], pk[9], pk[10], pk[11]);
    dst[3] = make_uint4(pk[12],pk[13],pk[14],pk[15]);
  }
  __syncthreads();

  // ---- phase 2: load A frags, barrier (frees AhG), MFMA conv ----
  const int lane = tid & 63, w = tid >> 6;
  const int h = w & 1, nh = w >> 1;
  const int r16 = lane & 15, hi4 = lane >> 4;
  const int c0 = hi4*8;
  const int oc0 = h*16 + hi4*4;

  const __fp16* Ab = AhG + (h ? 3328 : 0);
  const int As  = h ? 232 : 104;
  const int njj = h ? 7 : 3;
  f16x8 aF[7], aG[7];
#pragma unroll 7
  for (int jj = 0; jj < 7; ++jj) if (jj < njj){
    aF[jj] = *reinterpret_cast<const f16x8*>(&Ab[r16*As + jj*32 + c0]);
    aG[jj] = *reinterpret_cast<const f16x8*>(&Ab[(16 + r16)*As + jj*32 + c0]);
  }
  f16x8 ar = *reinterpret_cast<const f16x8*>(&rwh[(h*16 + r16)*40 + c0]);
  float fb4[4], gb4[4], rb4[4];
#pragma unroll
  for (int i2 = 0; i2 < 4; ++i2){
    fb4[i2] = fbias[oc0+i2]; gb4[i2] = gbias[oc0+i2]; rb4[i2] = rbv[oc0+i2];
  }
  __syncthreads();                    // all A frags in regs -> AhG reusable
  __fp16* gh = AhG;                   // gh[t][b][c], stride 40

  float sv[4] = {0.f, 0.f, 0.f, 0.f};
#pragma unroll
  for (int q = 0; q < 6; ++q){
    int nt = nh*6 + q;
    f32x4 accf = {0.f,0.f,0.f,0.f}, accg = {0.f,0.f,0.f,0.f};
#pragma unroll 7
    for (int jj = 0; jj < 7; ++jj) if (jj < njj){
      int tp = nt + jj; if (tp >= 12) tp -= 12;
      f16x8 bf = *reinterpret_cast<const f16x8*>(&xh[(tp*16 + r16)*40 + c0]);
      accf = __builtin_amdgcn_mfma_f32_16x16x32_f16(aF[jj], bf, accf, 0, 0, 0);
      accg = __builtin_amdgcn_mfma_f32_16x16x32_f16(aG[jj], bf, accg, 0, 0, 0);
    }
    float gv4[4];
#pragma unroll
    for (int i2 = 0; i2 < 4; ++i2){
      float fv = ftanh(accf[i2] + fb4[i2]);
      float gg = fsig(accg[i2] + gb4[i2]);
      gv4[i2] = fv * gg;
      sv[i2] = fmaf(gv4[i2], skwv[(oc0+i2)*12 + nt], sv[i2]);
    }
    *reinterpret_cast<uint2*>(&gh[(nt*16 + r16)*40 + oc0]) =
        make_uint2(pkh(gv4[0], gv4[1]), pkh(gv4[2], gv4[3]));
  }
#pragma unroll
  for (int i2 = 0; i2 < 4; ++i2)
    skred[((oc0+i2)*16 + r16)*2 + nh] = sv[i2];
  __syncthreads();

  // ---- phase 3: skip finalize + residual GEMM + epilogue + stat atomics ----
  for (int e = tid; e < 512; e += 256){
    int b = e >> 5, oc = e & 31;
    float sk = skred[(oc*16+b)*2] + skred[(oc*16+b)*2+1] + skbv[oc];
    size_t so = ((size_t)b*NN + n)*32 + oc;
    if (layer == 0){
      float s0 = s0bv[oc];
#pragma unroll
      for (int r = 0; r < 24; ++r) s0 = fmaf(xin[b*24+r], s0wv[oc*24+r], s0);
      skipbuf[so] = sk + s0;
    } else {
      skipbuf[so] += sk;
    }
  }
  {
    float s1 = 0.f, s2 = 0.f;
#pragma unroll
    for (int q = 0; q < 6; ++q){
      int nt = nh*6 + q;
      f16x8 bg = *reinterpret_cast<const f16x8*>(&gh[(nt*16 + r16)*40 + c0]);
      f32x4 z = {0.f,0.f,0.f,0.f};
      f32x4 acc = __builtin_amdgcn_mfma_f32_16x16x32_f16(ar, bg, z, 0, 0, 0);
      uint2 xu = *reinterpret_cast<const uint2*>(&xh[(nt*16 + r16)*40 + oc0]);
      U32H2 ua, ub; ua.u = xu.x; ub.u = xu.y;
      float o0 = acc[0] + rb4[0] + (float)ua.h[0];
      float o1 = acc[1] + rb4[1] + (float)ua.h[1];
      float o2 = acc[2] + rb4[2] + (float)ub.h[0];
      float o3 = acc[3] + rb4[3] + (float)ub.h[1];
      *reinterpret_cast<uint2*>(
          xbuf + (((size_t)r16*NN + n)*12 + nt)*32 + oc0) =
          make_uint2(pkh(o0, o1), pkh(o2, o3));
      s1 += o0 + o1 + o2 + o3;
      s2 = fmaf(o0,o0, fmaf(o1,o1, fmaf(o2,o2, fmaf(o3,o3, s2))));
    }
    s1 += __shfl_xor(s1, 16); s2 += __shfl_xor(s2, 16);
    s1 += __shfl_xor(s1, 32); s2 += __shfl_xor(s2, 32);
    if (hi4 == 0){
      wred[(w*16 + r16)*2]     = s1;
      wred[(w*16 + r16)*2 + 1] = s2;
    }
  }
  __syncthreads();
  if (tid < 16){
    float a1 = 0.f, a2 = 0.f;
    for (int w2 = 0; w2 < 4; ++w2){
      a1 += wred[(w2*16 + tid)*2];
      a2 += wred[(w2*16 + tid)*2 + 1];
    }
    atomicAdd(&stats[layer*32 + tid], a1);
    atomicAdd(&stats[layer*32 + 16 + tid], a2);
  }
}

__global__ __launch_bounds__(256) void k_final(
    const __fp16* __restrict__ xbuf, const float* __restrict__ skipbuf,
    const float* __restrict__ stats,
    const float* __restrict__ lnw_all, const float* __restrict__ lnb_all,
    const float* __restrict__ skEw, const float* __restrict__ skEb,
    const float* __restrict__ e1w, const float* __restrict__ e1b,
    const float* __restrict__ e2w, const float* __restrict__ e2b,
    float* __restrict__ out)
{
  __shared__ float lnw[384], lnb[384], skE[384];
  __shared__ float e1[32*33];
  __shared__ float e1bv[32], e2v[32], skEbv[32];
  __shared__ float muv[16], rsv[16];
  __shared__ float skf[8][33];
  const int tid = threadIdx.x, n = blockIdx.x;
  for (int i = tid; i < 384; i += 256){
    int c = i/12, t = i%12;
    size_t o = (((size_t)2*32 + c)*NN + n)*12 + t;
    lnw[i] = lnw_all[o]; lnb[i] = lnb_all[o];
    skE[i] = skEw[i];
  }
  for (int i = tid; i < 1024; i += 256) e1[(i>>5)*33 + (i&31)] = e1w[i];
  if (tid < 32){ e1bv[tid] = e1b[tid]; e2v[tid] = e2w[tid]; skEbv[tid] = skEb[tid]; }
  if (tid < 16){
    float S1 = stats[64+tid], S2 = stats[80+tid];
    const float M = 768000.0f;
    float mu = S1/M; muv[tid] = mu;
    rsv[tid] = rsqrtf(S2/M - mu*mu + 1e-5f);
  }
  __syncthreads();
  const float e2b0 = e2b[0];
  for (int bo = 0; bo < 2; ++bo){
    const int g = tid >> 5, c = tid & 31, b = bo*8 + g;
    float xr[12];
#pragma unroll
    for (int t = 0; t < 12; ++t)
      xr[t] = (float)xbuf[(((size_t)b*NN + n)*12 + t)*32 + c];
    const float mu = muv[b], rs = rsv[b];
    float se = 0.0f;
#pragma unroll
    for (int t = 0; t < 12; ++t){
      float xv = fmaf((xr[t]-mu)*rs, lnw[c*12+t], lnb[c*12+t]);
      se = fmaf(xv, skE[c*12+t], se);
    }
    float sk = se + skEbv[c] + skipbuf[((size_t)b*NN+n)*32 + c];
    skf[g][c] = fmaxf(sk, 0.0f);
    __syncthreads();
    float acc = e1bv[c];
#pragma unroll
    for (int cc = 0; cc < 32; ++cc) acc = fmaf(skf[g][cc], e1[c*33+cc], acc);
    float y1 = fmaxf(acc, 0.0f);
    float part = y1 * e2v[c];
#pragma unroll
    for (int off = 16; off > 0; off >>= 1) part += __shfl_down(part, off, 32);
    if (c == 0) out[(size_t)b*NN + n] = part + e2b0;
    __syncthreads();
  }
}

extern "C" void kernel_launch(void* const* d_in, const int* in_sizes, int n_in,
                              void* d_out, int out_size, void* d_ws, size_t ws_size,
                              hipStream_t stream)
{
  (void)in_sizes; (void)n_in; (void)out_size; (void)ws_size;
  const float* input   = (const float*)d_in[0];
  const float* adj     = (const float*)d_in[1];
  const float* charac  = (const float*)d_in[2];
  const float* Wcw     = (const float*)d_in[3];
  const float* bcw     = (const float*)d_in[4];
  const float* Wcb     = (const float*)d_in[5];
  const float* bcb     = (const float*)d_in[6];
  const float* Wgw     = (const float*)d_in[7];
  const float* bgw     = (const float*)d_in[8];
  const float* Wgb     = (const float*)d_in[9];
  const float* bgb     = (const float*)d_in[10];
  const float* Wrw     = (const float*)d_in[11];
  const float* brw     = (const float*)d_in[12];
  const float* Wrb     = (const float*)d_in[13];
  const float* brb     = (const float*)d_in[14];
  const float* start_w = (const float*)d_in[15];
  const float* start_b = (const float*)d_in[16];
  const float* sk0w    = (const float*)d_in[17];
  const float* sk0b    = (const float*)d_in[18];
  const float* skw     = (const float*)d_in[19];
  const float* skb     = (const float*)d_in[20];
  const float* skEw    = (const float*)d_in[21];
  const float* skEb    = (const float*)d_in[22];
  const float* lnw     = (const float*)d_in[23];
  const float* lnb     = (const float*)d_in[24];
  const float* e1w     = (const float*)d_in[25];
  const float* e1b     = (const float*)d_in[26];
  const float* e2w     = (const float*)d_in[27];
  const float* e2b     = (const float*)d_in[28];

  float* ws     = (float*)d_ws;
  __fp16* xbuf  = (__fp16*)(ws + XOFF);
  float* skipb  = ws + SKOFF;
  float* chbuf  = ws + CHOFF;
  float* cmbuf  = ws + CMOFF;
  float* stats  = ws + STOFF;
  float* PKW    = ws + PKWOFF;
  float* PKB    = ws + PKBOFF;
  float* PKR    = ws + PKROFF;
  float* outp   = (float*)d_out;

  k_init<<<1, 128, 0, stream>>>(stats);
  k_prep<<<86, 256, 0, stream>>>(Wcw, bcw, Wgw, bgw, Wrw, brw,
                                 input, charac, PKW, PKB, PKR, cmbuf);
  k_ch<<<NN, 256, 0, stream>>>(adj, cmbuf, chbuf);
  for (int layer = 0; layer < 3; ++layer){
    k_layer<<<NN, 256, 0, stream>>>(layer, xbuf, skipb, chbuf, stats, input,
        PKW, PKB, PKR, Wcb, bcb, Wgb, bgb, Wrb, brb,
        start_w, start_b, sk0w, sk0b, skw, skb, lnw, lnb);
  }
  k_final<<<NN, 256, 0, stream>>>(xbuf, skipb, stats, lnw, lnb,
      skEw, skEb, e1w, e1b, e2w, e2b, outp);
}

// Round 16
// 191.085 us; speedup vs baseline: 1.0497x; 1.0497x over previous
//
#include <hip/hip_runtime.h>

#define NN 2000
#define TT 12

// workspace layout (in floats)
#define XOFF    0          // x buffer f16: (B,N,T,C) f16 = 6,144,000 floats
#define SKOFF   6144000    // skip: (B,N,C) f32
#define CHOFF   7168000    // ch: N*4
#define CMOFF   7176000    // char_m: N*4
#define STOFF   7184000    // stats: 96
#define PARTOFF 7184100    // per-node stat partials: 2000*32
#define PKWOFF  7248100    // packed conv+gate rank weights f32 [layer][o][u][c]: 13824*8
#define PKBOFF  7358692    // packed conv+gate rank biases f32 [layer][o][u][c]: 13824*2
#define PKROFF  7386340    // packed residual rank weights f32: 3072*8

typedef __fp16 f16x8 __attribute__((ext_vector_type(8)));
typedef __fp16 h2    __attribute__((ext_vector_type(2)));
typedef float  f32x4 __attribute__((ext_vector_type(4)));

union U32H2 { unsigned int u; __fp16 h[2]; h2 v; };
__device__ __forceinline__ unsigned int pkh(float a, float b){
  U32H2 x; x.h[0] = (__fp16)a; x.h[1] = (__fp16)b; return x.u;
}
__device__ __forceinline__ h2 u2h(unsigned int u){ U32H2 x; x.u = u; return x.v; }
__device__ __forceinline__ unsigned int h2u(h2 v){ U32H2 x; x.v = v; return x.u; }
__device__ __forceinline__ float fsig(float x){ return 1.0f/(1.0f + __expf(-x)); }
__device__ __forceinline__ float ftanh(float x){ return 1.0f - 2.0f/(1.0f + __expf(2.0f*x)); }

// fused: weight packing (cols < 13824) + month-characteristic mean (idx < 8000)
__global__ __launch_bounds__(256) void k_prep(
    const float* __restrict__ Wcw, const float* __restrict__ bcw,
    const float* __restrict__ Wgw, const float* __restrict__ bgw,
    const float* __restrict__ Wrw, const float* __restrict__ brw,
    const float* __restrict__ input, const float* __restrict__ charac,
    float* __restrict__ PKW, float* __restrict__ PKB, float* __restrict__ PKR,
    float* __restrict__ cm)
{
  int col = blockIdx.x*256 + threadIdx.x;
  if (col < 13824){
    int layer = col / 4608;
    int i     = col - layer*4608;
    int o     = i / 576;
    int rem   = i - o*576;
    int c     = rem / 18;
    int u     = rem - c*18;
    size_t j  = (size_t)layer*4608 + o*576 + u*32 + c;
    float4 a = make_float4(Wcw[col], Wcw[13824+col], Wcw[27648+col], Wcw[41472+col]);
    float4 b = make_float4(Wgw[col], Wgw[13824+col], Wgw[27648+col], Wgw[41472+col]);
    *reinterpret_cast<float4*>(PKW + j*8)     = a;
    *reinterpret_cast<float4*>(PKW + j*8 + 4) = b;
    *reinterpret_cast<float2*>(PKB + j*2) = make_float2(bcw[col], bgw[col]);
  }
  if (col < 3072){
    float4 r = make_float4(Wrw[col], Wrw[3072+col], Wrw[6144+col], Wrw[9216+col]);
    *reinterpret_cast<float4*>(PKR + (size_t)col*8) = r;
    PKR[(size_t)col*8 + 4] = brw[col];
  }
  if (col < NN*4){
    int n = col >> 2, r = col & 3;
    int mv = (int)input[TT];
    int m = ((mv % 12) + 12) % 12;
    int m0 = (m + 11) % 12, m2 = (m + 1) % 12;
    const float* base = charac + n*48;
    cm[col] = (base[m0*4+r] + base[m*4+r] + base[m2*4+r]) * (1.0f/3.0f);
  }
}

__global__ __launch_bounds__(256) void k_ch(const float* __restrict__ adj,
                                            const float* __restrict__ cm,
                                            float* __restrict__ ch)
{
  __shared__ float red[256][4];
  int n = blockIdx.x, t = threadIdx.x;
  float s0=0.f, s1=0.f, s2=0.f, s3=0.f;
  const float* arow = adj + (size_t)n*NN;
  for (int c = t; c < NN; c += 256){
    float a = arow[c];
    float4 v = *reinterpret_cast<const float4*>(cm + c*4);
    s0 = fmaf(a, v.x, s0); s1 = fmaf(a, v.y, s1);
    s2 = fmaf(a, v.z, s2); s3 = fmaf(a, v.w, s3);
  }
  red[t][0]=s0; red[t][1]=s1; red[t][2]=s2; red[t][3]=s3;
  __syncthreads();
  for (int off = 128; off > 0; off >>= 1){
    if (t < off){
      red[t][0]+=red[t+off][0]; red[t][1]+=red[t+off][1];
      red[t][2]+=red[t+off][2]; red[t][3]+=red[t+off][3];
    }
    __syncthreads();
  }
  if (t < 4) ch[n*4+t] = red[0][t];
}

// per-layer stat reduction
__global__ __launch_bounds__(256) void k_stats(
    int layer, const float* __restrict__ parts, float* __restrict__ stats)
{
  __shared__ float red[256];
  const int j = blockIdx.x, tid = threadIdx.x;
  float s = 0.f;
  for (int i = tid; i < NN; i += 256) s += parts[(size_t)i*32 + j];
  red[tid] = s;
  __syncthreads();
  for (int off = 128; off > 0; off >>= 1){
    if (tid < off) red[tid] += red[tid+off];
    __syncthreads();
  }
  if (tid == 0) stats[layer*32 + j] = red[0];
}

// ---------------------------------------------------------------------------
// k_layer: R14 structure (proven 58 us): parts-based stats, bias spread 96.
// ---------------------------------------------------------------------------
__global__ __launch_bounds__(256,3) void k_layer(
    int layer,
    __fp16* __restrict__ xbuf, float* __restrict__ skipbuf,
    const float* __restrict__ ch, const float* __restrict__ stats,
    float* __restrict__ parts,
    const float* __restrict__ input,
    const float* __restrict__ PKW, const float* __restrict__ PKB,
    const float* __restrict__ PKR,
    const float* __restrict__ Wcb, const float* __restrict__ bcb,
    const float* __restrict__ Wgb, const float* __restrict__ bgb,
    const float* __restrict__ Wrb, const float* __restrict__ brb,
    const float* __restrict__ start_w, const float* __restrict__ start_b,
    const float* __restrict__ sk0w, const float* __restrict__ sk0b,
    const float* __restrict__ skw_all, const float* __restrict__ skb_all,
    const float* __restrict__ lnw_all, const float* __restrict__ lnb_all)
{
  __shared__ __fp16 AhG[10752];      // A tiles, later gh overlay
  __shared__ __fp16 xh[7680];        // [t][b][c] stride 40
  __shared__ __fp16 rwh[1280];
  __shared__ float skred[1024];
  __shared__ float wred[128];
  __shared__ float ubuf[1280];
  __shared__ float skwv[384];
  __shared__ float skbv[32], fbias[32], gbias[32], rbv[32];
  __shared__ float muv[16], rsv[16];

  const int tid = threadIdx.x;
  const int n = blockIdx.x;

  float* swv  = ubuf;        // 64   (layer 0)
  float* sbv  = ubuf + 64;   // 32
  float* s0wv = ubuf + 96;   // 768
  float* s0bv = ubuf + 864;  // 32
  float* xin  = ubuf + 896;  // 384 = 16 b x 24
  __fp16* lnh = reinterpret_cast<__fp16*>(ubuf);  // layer>0: [0:384) lnw [t][c], [384:768) lnb

  const float c0v = ch[n*4+0], c1v = ch[n*4+1], c2v = ch[n*4+2], c3v = ch[n*4+3];

  // ---- phase 0 constants ----
  for (int i = tid; i < 32; i += 256) skbv[i] = skb_all[layer*32+i];
  for (int i = tid; i < 384; i += 256) skwv[i] = skw_all[layer*384+i];
  if (layer == 0){
    for (int i = tid; i < 64; i += 256) swv[i] = start_w[i];
    for (int i = tid; i < 32; i += 256){ sbv[i] = start_b[i]; s0bv[i] = sk0b[i]; }
    for (int i = tid; i < 768; i += 256) s0wv[i] = sk0w[i];
    for (int i = tid; i < 384; i += 256){
      int bb = i/24, r = i%24, d = r/12, t = r%12;
      xin[i] = input[(((size_t)bb*2 + d)*NN + n)*13 + t];
    }
  } else {
    for (int i = tid; i < 384; i += 256){
      int c = i/12, t = i%12;
      size_t o = (((size_t)(layer-1)*32 + c)*NN + n)*12 + t;
      lnh[t*32+c]       = (__fp16)lnw_all[o];
      lnh[384 + t*32+c] = (__fp16)lnb_all[o];
    }
    if (tid < 16){
      float S1 = stats[(layer-1)*32 + tid];
      float S2 = stats[(layer-1)*32 + 16 + tid];
      const float M = 768000.0f;
      float mu = S1 / M;
      muv[tid] = mu;
      rsv[tid] = rsqrtf(S2/M - mu*mu + 1e-5f);
    }
  }

  // ---- phase 1: weight gen, o = tid>>5 constant, u compile-time unrolled ----
  {
    const int cc = tid & 31;
    const int o  = tid >> 5;
    const int o104 = o*104, o232 = o*232;
    const float* pw  = PKW + (size_t)layer*4608*8 + ((size_t)o*576 + cc)*8;
    const float* pbp = PKB + (size_t)layer*4608*2 + ((size_t)o*576 + cc)*2;
#pragma unroll
    for (int u = 0; u < 18; ++u){
      const int s    = (u >= 2) + (u >= 5) + (u >= 11);
      const int lo   = (s == 0) ? 0 : ((s == 1) ? 2 : ((s == 2) ? 5 : 11));
      const int jj   = u - lo;
      const int strd = (s >= 2) ? 232 : 104;
      const int base = ((s >= 2) ? 3328 : 0) + ((s & 1) << 3)*strd + jj*32;
      const int ooff = (s >= 2) ? o232 : o104;
      float4 pwf = *reinterpret_cast<const float4*>(pw + (size_t)u*256);
      float4 pwg = *reinterpret_cast<const float4*>(pw + (size_t)u*256 + 4);
      float2 pb  = *reinterpret_cast<const float2*>(pbp + (size_t)u*64);
      float wf = fmaf(c0v, pwf.x, fmaf(c1v, pwf.y,
                 fmaf(c2v, pwf.z, fmaf(c3v, pwf.w, pb.x))));
      float wg = fmaf(c0v, pwg.x, fmaf(c1v, pwg.y,
                 fmaf(c2v, pwg.z, fmaf(c3v, pwg.w, pb.y))));
      AhG[base + ooff + cc]             = (__fp16)wf;
      AhG[base + ooff + cc + 16*strd]   = (__fp16)wg;
    }
  }
  // zero padding slots (s=0 jj=2; s=2 jj=6)
  for (int i = tid; i < 1024; i += 256){
    int grp = i >> 8, rem = i & 255, r = rem >> 5, c = rem & 31;
    int base = (grp < 2) ? 0 : 3328;
    int strd = (grp < 2) ? 104 : 232;
    int off  = (grp < 2) ? 64 : 192;
    int gofs = (grp & 1) ? 16*strd : 0;
    AhG[base + gofs + r*strd + off + c] = (__fp16)0.f;
  }
  for (int i = tid; i < 1024; i += 256){
    int col = layer*1024 + i;
    float4 pr = *reinterpret_cast<const float4*>(PKR + (size_t)col*8);
    float rb = PKR[(size_t)col*8 + 4];
    float v = fmaf(c0v, pr.x, fmaf(c1v, pr.y,
              fmaf(c2v, pr.z, fmaf(c3v, pr.w, rb))));
    rwh[(i>>5)*40 + (i&31)] = (__fp16)v;
  }
  if (tid < 96){
    int which = tid >> 5, oc = tid & 31;
    if (which < 2){
      int s = oc >> 3;
      int v = ((n&3)<<3) + (oc&7);             // bias reshuffle: column
      int col = layer*32 + v;
      float cb0 = ch[(s*500 + (n>>2))*4 + 0];
      float cb1 = ch[(s*500 + (n>>2))*4 + 1];
      float cb2 = ch[(s*500 + (n>>2))*4 + 2];
      float cb3 = ch[(s*500 + (n>>2))*4 + 3];
      const float* Wb = which ? Wgb : Wcb;
      const float* bb = which ? bgb : bcb;
      float out = fmaf(cb0, Wb[col], fmaf(cb1, Wb[96+col],
                  fmaf(cb2, Wb[192+col], fmaf(cb3, Wb[288+col], bb[col]))));
      if (which) gbias[oc] = out; else fbias[oc] = out;
    } else {
      int colr = layer*32 + oc;
      rbv[oc] = fmaf(c0v, Wrb[colr], fmaf(c1v, Wrb[96+colr],
                fmaf(c2v, Wrb[192+colr], fmaf(c3v, Wrb[288+colr], brb[colr]))));
    }
  }
  __syncthreads();

  // ---- staging: xh[t][b][c] f16 (layer>0 path fully packed f16) ----
  if (tid < 192){
    int b = tid & 15, t = tid >> 4;
    unsigned int pk[16];
    if (layer == 0){
      float xa = xin[b*24 + t], xb2 = xin[b*24 + 12 + t];
      float xv[32];
#pragma unroll
      for (int c = 0; c < 32; ++c)
        xv[c] = fmaf(swv[c*2], xa, fmaf(swv[c*2+1], xb2, sbv[c]));
#pragma unroll
      for (int j = 0; j < 16; ++j) pk[j] = pkh(xv[2*j], xv[2*j+1]);
    } else {
      const uint4* src = reinterpret_cast<const uint4*>(
          xbuf + (((size_t)b*NN + n)*12 + t)*32);
      uint4 u0 = src[0], u1 = src[1], u2 = src[2], u3 = src[3];
      unsigned int uu[16] = {u0.x,u0.y,u0.z,u0.w, u1.x,u1.y,u1.z,u1.w,
                             u2.x,u2.y,u2.z,u2.w, u3.x,u3.y,u3.z,u3.w};
      __fp16 muh = (__fp16)muv[b], rsh = (__fp16)rsv[b];
      h2 mu2; mu2.x = muh; mu2.y = muh;
      h2 rs2; rs2.x = rsh; rs2.y = rsh;
      const h2* lnw2 = reinterpret_cast<const h2*>(lnh + t*32);
      const h2* lnb2 = reinterpret_cast<const h2*>(lnh + 384 + t*32);
#pragma unroll
      for (int j = 0; j < 16; ++j){
        h2 v = u2h(uu[j]);
        h2 r = (v - mu2) * rs2;
        h2 x2 = r * lnw2[j] + lnb2[j];
        pk[j] = h2u(x2);
      }
    }
    uint4* dst = reinterpret_cast<uint4*>(&xh[(t*16 + b)*40]);
    dst[0] = make_uint4(pk[0], pk[1], pk[2], pk[3]);
    dst[1] = make_uint4(pk[4], pk[5], pk[6], pk[7]);
    dst[2] = make_uint4(pk[8], pk[9], pk[10], pk[11]);
    dst[3] = make_uint4(pk[12],pk[13],pk[14],pk[15]);
  }
  __syncthreads();

  // ---- phase 2: load A frags, barrier (frees AhG), MFMA conv ----
  const int lane = tid & 63, w = tid >> 6;
  const int h = w & 1, nh = w >> 1;
  const int r16 = lane & 15, hi4 = lane >> 4;
  const int c0 = hi4*8;
  const int oc0 = h*16 + hi4*4;

  const __fp16* Ab = AhG + (h ? 3328 : 0);
  const int As  = h ? 232 : 104;
  const int njj = h ? 7 : 3;
  f16x8 aF[7], aG[7];
#pragma unroll 7
  for (int jj = 0; jj < 7; ++jj) if (jj < njj){
    aF[jj] = *reinterpret_cast<const f16x8*>(&Ab[r16*As + jj*32 + c0]);
    aG[jj] = *reinterpret_cast<const f16x8*>(&Ab[(16 + r16)*As + jj*32 + c0]);
  }
  f16x8 ar = *reinterpret_cast<const f16x8*>(&rwh[(h*16 + r16)*40 + c0]);
  float fb4[4], gb4[4], rb4[4];
#pragma unroll
  for (int i2 = 0; i2 < 4; ++i2){
    fb4[i2] = fbias[oc0+i2]; gb4[i2] = gbias[oc0+i2]; rb4[i2] = rbv[oc0+i2];
  }
  __syncthreads();                    // all A frags in regs -> AhG reusable
  __fp16* gh = AhG;                   // gh[t][b][c], stride 40

  float sv[4] = {0.f, 0.f, 0.f, 0.f};
#pragma unroll
  for (int q = 0; q < 6; ++q){
    int nt = nh*6 + q;
    f32x4 accf = {0.f,0.f,0.f,0.f}, accg = {0.f,0.f,0.f,0.f};
#pragma unroll 7
    for (int jj = 0; jj < 7; ++jj) if (jj < njj){
      int tp = nt + jj; if (tp >= 12) tp -= 12;
      f16x8 bf = *reinterpret_cast<const f16x8*>(&xh[(tp*16 + r16)*40 + c0]);
      accf = __builtin_amdgcn_mfma_f32_16x16x32_f16(aF[jj], bf, accf, 0, 0, 0);
      accg = __builtin_amdgcn_mfma_f32_16x16x32_f16(aG[jj], bf, accg, 0, 0, 0);
    }
    float gv4[4];
#pragma unroll
    for (int i2 = 0; i2 < 4; ++i2){
      float fv = ftanh(accf[i2] + fb4[i2]);
      float gg = fsig(accg[i2] + gb4[i2]);
      gv4[i2] = fv * gg;
      sv[i2] = fmaf(gv4[i2], skwv[(oc0+i2)*12 + nt], sv[i2]);
    }
    *reinterpret_cast<uint2*>(&gh[(nt*16 + r16)*40 + oc0]) =
        make_uint2(pkh(gv4[0], gv4[1]), pkh(gv4[2], gv4[3]));
  }
#pragma unroll
  for (int i2 = 0; i2 < 4; ++i2)
    skred[((oc0+i2)*16 + r16)*2 + nh] = sv[i2];
  __syncthreads();

  // ---- phase 3: skip finalize + residual GEMM + epilogue + stat partials ----
  for (int e = tid; e < 512; e += 256){
    int b = e >> 5, oc = e & 31;
    float sk = skred[(oc*16+b)*2] + skred[(oc*16+b)*2+1] + skbv[oc];
    size_t so = ((size_t)b*NN + n)*32 + oc;
    if (layer == 0){
      float s0 = s0bv[oc];
#pragma unroll
      for (int r = 0; r < 24; ++r) s0 = fmaf(xin[b*24+r], s0wv[oc*24+r], s0);
      skipbuf[so] = sk + s0;
    } else {
      skipbuf[so] += sk;
    }
  }
  {
    float s1 = 0.f, s2 = 0.f;
#pragma unroll
    for (int q = 0; q < 6; ++q){
      int nt = nh*6 + q;
      f16x8 bg = *reinterpret_cast<const f16x8*>(&gh[(nt*16 + r16)*40 + c0]);
      f32x4 z = {0.f,0.f,0.f,0.f};
      f32x4 acc = __builtin_amdgcn_mfma_f32_16x16x32_f16(ar, bg, z, 0, 0, 0);
      uint2 xu = *reinterpret_cast<const uint2*>(&xh[(nt*16 + r16)*40 + oc0]);
      U32H2 ua, ub; ua.u = xu.x; ub.u = xu.y;
      float o0 = acc[0] + rb4[0] + (float)ua.h[0];
      float o1 = acc[1] + rb4[1] + (float)ua.h[1];
      float o2 = acc[2] + rb4[2] + (float)ub.h[0];
      float o3 = acc[3] + rb4[3] + (float)ub.h[1];
      *reinterpret_cast<uint2*>(
          xbuf + (((size_t)r16*NN + n)*12 + nt)*32 + oc0) =
          make_uint2(pkh(o0, o1), pkh(o2, o3));
      s1 += o0 + o1 + o2 + o3;
      s2 = fmaf(o0,o0, fmaf(o1,o1, fmaf(o2,o2, fmaf(o3,o3, s2))));
    }
    s1 += __shfl_xor(s1, 16); s2 += __shfl_xor(s2, 16);
    s1 += __shfl_xor(s1, 32); s2 += __shfl_xor(s2, 32);
    if (hi4 == 0){
      wred[(w*16 + r16)*2]     = s1;
      wred[(w*16 + r16)*2 + 1] = s2;
    }
  }
  __syncthreads();
  if (tid < 16){
    float a1 = 0.f, a2 = 0.f;
    for (int w2 = 0; w2 < 4; ++w2){
      a1 += wred[(w2*16 + tid)*2];
      a2 += wred[(w2*16 + tid)*2 + 1];
    }
    parts[(size_t)n*32 + tid]      = a1;
    parts[(size_t)n*32 + 16 + tid] = a2;
  }
}

__global__ __launch_bounds__(256) void k_final(
    const __fp16* __restrict__ xbuf, const float* __restrict__ skipbuf,
    const float* __restrict__ stats,
    const float* __restrict__ lnw_all, const float* __restrict__ lnb_all,
    const float* __restrict__ skEw, const float* __restrict__ skEb,
    const float* __restrict__ e1w, const float* __restrict__ e1b,
    const float* __restrict__ e2w, const float* __restrict__ e2b,
    float* __restrict__ out)
{
  __shared__ float lnw[384], lnb[384], skE[384];
  __shared__ float e1[32*33];
  __shared__ float e1bv[32], e2v[32], skEbv[32];
  __shared__ float muv[16], rsv[16];
  __shared__ float skf[8][33];
  const int tid = threadIdx.x, n = blockIdx.x;
  for (int i = tid; i < 384; i += 256){
    int c = i/12, t = i%12;
    size_t o = (((size_t)2*32 + c)*NN + n)*12 + t;
    lnw[i] = lnw_all[o]; lnb[i] = lnb_all[o];
    skE[i] = skEw[i];
  }
  for (int i = tid; i < 1024; i += 256) e1[(i>>5)*33 + (i&31)] = e1w[i];
  if (tid < 32){ e1bv[tid] = e1b[tid]; e2v[tid] = e2w[tid]; skEbv[tid] = skEb[tid]; }
  if (tid < 16){
    float S1 = stats[64+tid], S2 = stats[80+tid];
    const float M = 768000.0f;
    float mu = S1/M; muv[tid] = mu;
    rsv[tid] = rsqrtf(S2/M - mu*mu + 1e-5f);
  }
  __syncthreads();
  const float e2b0 = e2b[0];
  for (int bo = 0; bo < 2; ++bo){
    const int g = tid >> 5, c = tid & 31, b = bo*8 + g;
    float xr[12];
#pragma unroll
    for (int t = 0; t < 12; ++t)
      xr[t] = (float)xbuf[(((size_t)b*NN + n)*12 + t)*32 + c];
    const float mu = muv[b], rs = rsv[b];
    float se = 0.0f;
#pragma unroll
    for (int t = 0; t < 12; ++t){
      float xv = fmaf((xr[t]-mu)*rs, lnw[c*12+t], lnb[c*12+t]);
      se = fmaf(xv, skE[c*12+t], se);
    }
    float sk = se + skEbv[c] + skipbuf[((size_t)b*NN+n)*32 + c];
    skf[g][c] = fmaxf(sk, 0.0f);
    __syncthreads();
    float acc = e1bv[c];
#pragma unroll
    for (int cc = 0; cc < 32; ++cc) acc = fmaf(skf[g][cc], e1[c*33+cc], acc);
    float y1 = fmaxf(acc, 0.0f);
    float part = y1 * e2v[c];
#pragma unroll
    for (int off = 16; off > 0; off >>= 1) part += __shfl_down(part, off, 32);
    if (c == 0) out[(size_t)b*NN + n] = part + e2b0;
    __syncthreads();
  }
}

extern "C" void kernel_launch(void* const* d_in, const int* in_sizes, int n_in,
                              void* d_out, int out_size, void* d_ws, size_t ws_size,
                              hipStream_t stream)
{
  (void)in_sizes; (void)n_in; (void)out_size; (void)ws_size;
  const float* input   = (const float*)d_in[0];
  const float* adj     = (const float*)d_in[1];
  const float* charac  = (const float*)d_in[2];
  const float* Wcw     = (const float*)d_in[3];
  const float* bcw     = (const float*)d_in[4];
  const float* Wcb     = (const float*)d_in[5];
  const float* bcb     = (const float*)d_in[6];
  const float* Wgw     = (const float*)d_in[7];
  const float* bgw     = (const float*)d_in[8];
  const float* Wgb     = (const float*)d_in[9];
  const float* bgb     = (const float*)d_in[10];
  const float* Wrw     = (const float*)d_in[11];
  const float* brw     = (const float*)d_in[12];
  const float* Wrb     = (const float*)d_in[13];
  const float* brb     = (const float*)d_in[14];
  const float* start_w = (const float*)d_in[15];
  const float* start_b = (const float*)d_in[16];
  const float* sk0w    = (const float*)d_in[17];
  const float* sk0b    = (const float*)d_in[18];
  const float* skw     = (const float*)d_in[19];
  const float* skb     = (const float*)d_in[20];
  const float* skEw    = (const float*)d_in[21];
  const float* skEb    = (const float*)d_in[22];
  const float* lnw     = (const float*)d_in[23];
  const float* lnb     = (const float*)d_in[24];
  const float* e1w     = (const float*)d_in[25];
  const float* e1b     = (const float*)d_in[26];
  const float* e2w     = (const float*)d_in[27];
  const float* e2b     = (const float*)d_in[28];

  float* ws     = (float*)d_ws;
  __fp16* xbuf  = (__fp16*)(ws + XOFF);
  float* skipb  = ws + SKOFF;
  float* chbuf  = ws + CHOFF;
  float* cmbuf  = ws + CMOFF;
  float* stats  = ws + STOFF;
  float* parts  = ws + PARTOFF;
  float* PKW    = ws + PKWOFF;
  float* PKB    = ws + PKBOFF;
  float* PKR    = ws + PKROFF;
  float* outp   = (float*)d_out;

  k_prep<<<86, 256, 0, stream>>>(Wcw, bcw, Wgw, bgw, Wrw, brw,
                                 input, charac, PKW, PKB, PKR, cmbuf);
  k_ch<<<NN, 256, 0, stream>>>(adj, cmbuf, chbuf);
  for (int layer = 0; layer < 3; ++layer){
    k_layer<<<NN, 256, 0, stream>>>(layer, xbuf, skipb, chbuf, stats, parts, input,
        PKW, PKB, PKR, Wcb, bcb, Wgb, bgb, Wrb, brb,
        start_w, start_b, sk0w, sk0b, skw, skb, lnw, lnb);
    k_stats<<<32, 256, 0, stream>>>(layer, parts, stats);
  }
  k_final<<<NN, 256, 0, stream>>>(xbuf, skipb, stats, lnw, lnb,
      skEw, skEb, e1w, e1b, e2w, e2b, outp);
}